// Round 11
// baseline (299.229 us; speedup 1.0000x reference)
//
#include <hip/hip_runtime.h>
#include <stdint.h>
#include <stddef.h>

#define NB 8
#define CC 192
#define C3 576
#define HGT 128
#define WID 128
#define HW 16384
#define NH 8
#define QKPL ((size_t)6291456)   // per (part*8+b) plane: 4096 u4-units * 192 cm * 8B

typedef short bf16x8 __attribute__((ext_vector_type(8)));
typedef float f32x4 __attribute__((ext_vector_type(4)));

__device__ __forceinline__ unsigned short f2bf(float f) {
  unsigned int u = __float_as_uint(f);
  u += 0x7fffu + ((u >> 16) & 1u);
  return (unsigned short)(u >> 16);
}
__device__ __forceinline__ float bf2f(unsigned short h) {
  return __uint_as_float(((unsigned int)h) << 16);
}
__device__ __forceinline__ float bflo(unsigned int v) {
  return __uint_as_float(v << 16);
}
__device__ __forceinline__ float bfhi(unsigned int v) {
  return __uint_as_float(v & 0xffff0000u);
}
__device__ __forceinline__ unsigned int pk2(float a, float b) {
  return (unsigned int)f2bf(a) | ((unsigned int)f2bf(b) << 16);
}
__device__ __forceinline__ void gl_lds16(const void* g, void* l) {
  __builtin_amdgcn_global_load_lds(
      (const __attribute__((address_space(1))) unsigned int*)(uintptr_t)g,
      (__attribute__((address_space(3))) unsigned int*)(uint32_t)(uintptr_t)l,
      16, 0, 0);
}
__device__ __forceinline__ int xcd_swz(int g, int n) {
  return (g & 7) * (n >> 3) + (g >> 3);
}

// ---------------- kwprep: w_qkv -> bf16 swizzled rows; also zeroes G/nq/nk
__global__ void kwprep(const float* __restrict__ wq, unsigned char* __restrict__ wb,
                       unsigned char* __restrict__ zero_region) {
  int f = blockIdx.x * 256 + threadIdx.x;
  if (f < 9984) *(uint4*)(zero_region + (size_t)f * 16) = (uint4){0, 0, 0, 0};
  if (f >= C3 * 24) return;
  int oc = f / 24, s = f % 24;
  unsigned int wv[4];
#pragma unroll
  for (int j = 0; j < 4; ++j)
    wv[j] = pk2(wq[oc * 192 + s * 8 + 2 * j], wq[oc * 192 + s * 8 + 2 * j + 1]);
  uint4 st; st.x = wv[0]; st.y = wv[1]; st.z = wv[2]; st.w = wv[3];
  *(uint4*)(wb + (size_t)oc * 384 + ((s ^ (oc & 7)) * 16)) = st;
}

// ---------------- kqkv v4: fused cast/transpose + qkv conv1x1, 52KB LDS, 3 blocks/CU
// q/k: DIRECT coalesced stores in 4px-unit layout (no TR, no extra barriers).
// v: TR transpose path (planar output). B half dbuf 2x12KB.
__global__ __launch_bounds__(256) void kqkv(const float* __restrict__ x,
                                            const unsigned char* __restrict__ wb,
                                            const float* __restrict__ bqkv,
                                            unsigned short* __restrict__ vout,
                                            unsigned char* __restrict__ qkout) {
  __shared__ __align__(16) unsigned char lds[53248];
  const int ABF = 0;       // A bf16 [24 s][64 p][16B] = 24576
  const int BB  = 24576;   // B half-tile dbuf 2 x 12288 (prologue: x-chunk staging)
  const int TR  = 49152;   // 4KB transpose buffer (v only)
  int wg = xcd_swz(blockIdx.x, gridDim.x);
  int t = wg & 255, b = wg >> 8;
  int p0 = t * 64;
  int tid = threadIdx.x;
  const unsigned char* gx = (const unsigned char*)(x + (size_t)b * CC * HW + p0);

  // ---- prologue: stage+repack x in 2 chunks of 96 channels through BB region
  int p = tid & 63, sg = tid >> 6;
#pragma unroll
  for (int ck = 0; ck < 2; ++ck) {
#pragma unroll
    for (int i = 0; i < 6; ++i) {
      int f = i * 256 + tid;
      int ch = ck * 96 + (f >> 4), seg = f & 15;
      gl_lds16(gx + ((size_t)ch * HW + seg * 4) * 4, lds + BB + f * 16);
    }
    asm volatile("s_waitcnt vmcnt(0)" ::: "memory");
    __syncthreads();
    const float* lx = (const float*)(lds + BB);
#pragma unroll
    for (int s3 = 0; s3 < 3; ++s3) {
      int s = sg * 3 + s3;
      unsigned int wv[4];
#pragma unroll
      for (int j = 0; j < 4; ++j)
        wv[j] = pk2(lx[(s * 8 + 2 * j) * 64 + p], lx[(s * 8 + 2 * j + 1) * 64 + p]);
      uint4 st; st.x = wv[0]; st.y = wv[1]; st.z = wv[2]; st.w = wv[3];
      *(uint4*)(lds + ABF + ((ck * 12 + s) * 64 + p) * 16) = st;
    }
    __syncthreads();
  }
  // ---- issue B half 0 (ot=0, hh=0)
#pragma unroll
  for (int i = 0; i < 3; ++i)
    gl_lds16(wb + i * 4096 + tid * 16, lds + BB + i * 4096 + tid * 16);

  int lane = tid & 63, w = tid >> 6;
  int l15 = lane & 15, gq = lane >> 4;
  int pw = w * 16;
  int s4 = w * 4 + gq;
  int vcv = tid >> 3, vx = tid & 7;    // v TR-read mapping
  size_t u4base = (size_t)(t * 16 + w * 4 + gq) * 1536;  // within (part,b) plane

  for (int j = 0; j < 18; ++j) {
    int ot = j >> 1, hh = j & 1, cur = j & 1;
    // counted wait: prev iter issued 2 global stores (q/k) or 1 (v) AFTER the
    // B-half prefetch -> vmcnt(N_stores) guarantees the prefetch has landed.
    if (j == 0)       { asm volatile("s_waitcnt vmcnt(0)" ::: "memory"); }
    else if (j <= 12) { asm volatile("s_waitcnt vmcnt(2)" ::: "memory"); }
    else              { asm volatile("s_waitcnt vmcnt(1)" ::: "memory"); }
    __builtin_amdgcn_s_barrier();
    __builtin_amdgcn_sched_barrier(0);
    float bias0 = bqkv[ot * 64 + hh * 32 + l15];
    float bias1 = bqkv[ot * 64 + hh * 32 + 16 + l15];
    if (j < 17) {
      int jn = j + 1;
      const unsigned char* gB = wb + (size_t)(jn >> 1) * 24576 + (jn & 1) * 12288;
#pragma unroll
      for (int i = 0; i < 3; ++i)
        gl_lds16(gB + i * 4096 + tid * 16, lds + BB + (cur ^ 1) * 12288 + i * 4096 + tid * 16);
    }
    __builtin_amdgcn_sched_barrier(0);   // pin prefetch issue before MFMA/stores
    f32x4 acc[2];
    acc[0] = (f32x4){0.f, 0.f, 0.f, 0.f};
    acc[1] = (f32x4){0.f, 0.f, 0.f, 0.f};
#pragma unroll
    for (int kk = 0; kk < 6; ++kk) {
      bf16x8 a = *(const bf16x8*)(lds + ABF + (((kk * 4 + gq) * 64) + pw + l15) * 16);
      int cb = kk * 64 + gq * 16;
#pragma unroll
      for (int nf2 = 0; nf2 < 2; ++nf2) {
        int r2 = nf2 * 16 + l15;
        bf16x8 bfr = *(const bf16x8*)(lds + BB + cur * 12288 + r2 * 384 + (cb ^ ((r2 & 7) << 4)));
        acc[nf2] = __builtin_amdgcn_mfma_f32_16x16x32_bf16(a, bfr, acc[nf2], 0, 0, 0);
      }
    }
    bool isq = (ot < 6);
    if (isq) {
      // direct coalesced store: lane's 4 consecutive px at one cm = one 8B unit
      int part = ot / 3, cm0 = (ot % 3) * 64 + hh * 32;
      unsigned char* gout = qkout + (size_t)(part * 8 + b) * QKPL + u4base;
#pragma unroll
      for (int nf2 = 0; nf2 < 2; ++nf2) {
        int cm = cm0 + nf2 * 16 + l15;
        float bs = nf2 ? bias1 : bias0;
        uint2 st;
        st.x = pk2(acc[nf2][0] + bs, acc[nf2][1] + bs);
        st.y = pk2(acc[nf2][2] + bs, acc[nf2][3] + bs);
        *(uint2*)(gout + cm * 8) = st;
      }
    } else {
      // v: TR transpose path (planar output needs px-contiguity per channel)
#pragma unroll
      for (int nf2 = 0; nf2 < 2; ++nf2) {
        int c = nf2 * 16 + l15;
        float bs = nf2 ? bias1 : bias0;
        uint2 st;
        st.x = pk2(acc[nf2][0] + bs, acc[nf2][1] + bs);
        st.y = pk2(acc[nf2][2] + bs, acc[nf2][3] + bs);
        *(uint2*)(lds + TR + c * 128 + ((s4 ^ (c & 15)) * 8)) = st;
      }
      asm volatile("s_waitcnt lgkmcnt(0)" ::: "memory");
      __builtin_amdgcn_s_barrier();
      __builtin_amdgcn_sched_barrier(0);
      uint2 q0 = *(const uint2*)(lds + TR + vcv * 128 + (((2 * vx) ^ (vcv & 15)) * 8));
      uint2 q1 = *(const uint2*)(lds + TR + vcv * 128 + (((2 * vx + 1) ^ (vcv & 15)) * 8));
      uint4 s0; s0.x = q0.x; s0.y = q0.y; s0.z = q1.x; s0.w = q1.y;
      *(uint4*)(vout + ((size_t)(b * CC + (ot - 6) * 64 + hh * 32 + vcv)) * HW +
                p0 + vx * 8) = s0;
    }
  }
}

// ---------------- kqk v4: dwconv(q,k) + Gram + norms, 2-row bands, 3 blocks/CU
// input layout: [(part*8+b)][u4 4096][cm 192][8B]; staged as [r 4][u4 32][cp 12][16B]
__global__ __launch_bounds__(256) void kqk(const unsigned char* __restrict__ qk,
                                           const float* __restrict__ wdw,
                                           const float* __restrict__ bdw,
                                           float* __restrict__ G,
                                           float* __restrict__ nq,
                                           float* __restrict__ nk) {
  __shared__ __align__(16) unsigned char lds[49168];
  const int FB = 0;
  const int ZP = 24576;
  const int STG = 24592;
  int wg = xcd_swz(blockIdx.x, gridDim.x);
  int band = wg & 63, h = (wg >> 6) & 7, b = wg >> 9;
  int y0 = band * 2;
  int tid = threadIdx.x;
  if (tid == 0) *(uint4*)(lds + ZP) = (uint4){0, 0, 0, 0};

  int lane = tid & 63, w = tid >> 6;
  int ch = tid >> 3, row = (tid >> 2) & 1, qt = tid & 3;
  int u0 = qt * 4;

#pragma unroll
  for (int p = 0; p < 2; ++p) {
    // ---- stage 4 rows (y0-1..y0+2) of part p
#pragma unroll
    for (int i = 0; i < 6; ++i) {
      int f = i * 256 + tid;
      int r = f / 384, unit = f % 384;
      int u4 = unit / 12, cp = unit % 12;
      int yy = y0 - 1 + r;
      if (yy >= 0 && yy < HGT)
        gl_lds16(qk + (size_t)(p * 8 + b) * QKPL +
                 (size_t)(yy * 32 + u4) * 1536 + (h * 24 + cp * 2) * 8,
                 lds + STG + f * 16);
      else
        *(uint4*)(lds + STG + f * 16) = (uint4){0, 0, 0, 0};
    }
    asm volatile("s_waitcnt vmcnt(0)" ::: "memory");
    __syncthreads();
    if (tid < 192) {
      int gc = p * 192 + h * 24 + ch;
      float wv[9];
#pragma unroll
      for (int j = 0; j < 9; ++j) wv[j] = wdw[gc * 9 + j];
      float bias = bdw[gc];
      const unsigned char* sb2 = lds + STG + (ch >> 1) * 16 + (ch & 1) * 8;
      unsigned char* fb = lds + FB + p * 12288 + (row * 4 + qt) * 1536 + ch * 16;
      unsigned int W[3][16];
#define LOADU3(dy_, m_, u_) { \
    uint2 ta, tb; \
    if ((u_) >= 0 && (u_) < 16) { \
      const unsigned char* ap = sb2 + (row + (dy_)) * 6144 + (2 * (u_)) * 192; \
      ta = *(const uint2*)(ap); \
      tb = *(const uint2*)(ap + 192); \
    } else { ta = (uint2){0, 0}; tb = (uint2){0, 0}; } \
    W[dy_][(m_) * 4 + 0] = ta.x; W[dy_][(m_) * 4 + 1] = ta.y; \
    W[dy_][(m_) * 4 + 2] = tb.x; W[dy_][(m_) * 4 + 3] = tb.y; }
#pragma unroll
      for (int dy = 0; dy < 3; ++dy) {
#pragma unroll
        for (int m = 0; m < 4; ++m) { LOADU3(dy, m, u0 - 1 + m); }
      }
      float nsum = 0.f;
#pragma unroll
      for (int c4 = 0; c4 < 2; ++c4) {
        if (c4 > 0) {
#pragma unroll
          for (int dy = 0; dy < 3; ++dy) {
#pragma unroll
            for (int e = 0; e < 8; ++e) W[dy][e] = W[dy][8 + e];
            LOADU3(dy, 2, u0 + 3);
            LOADU3(dy, 3, u0 + 4);
          }
        }
        float acc[16];
#pragma unroll
        for (int j = 0; j < 16; ++j) acc[j] = bias;
#pragma unroll
        for (int dy = 0; dy < 3; ++dy) {
          float f[18];
#pragma unroll
          for (int t2 = 0; t2 < 18; ++t2) {
            int rel = 7 + t2;
            unsigned int v = W[dy][rel >> 1];
            f[t2] = (rel & 1) ? bfhi(v) : bflo(v);
          }
#pragma unroll
          for (int j = 0; j < 16; ++j)
            acc[j] += f[j] * wv[dy * 3] + f[j + 1] * wv[dy * 3 + 1] + f[j + 2] * wv[dy * 3 + 2];
        }
#pragma unroll
        for (int j = 0; j < 16; ++j) nsum += acc[j] * acc[j];
        unsigned int pk[8];
#pragma unroll
        for (int e = 0; e < 8; ++e) pk[e] = pk2(acc[2 * e], acc[2 * e + 1]);
        uint4 s0; s0.x = pk[0]; s0.y = pk[1]; s0.z = pk[2]; s0.w = pk[3];
        uint4 s1; s1.x = pk[4]; s1.y = pk[5]; s1.z = pk[6]; s1.w = pk[7];
        *(uint4*)(fb + (c4 * 2) * 384) = s0;
        *(uint4*)(fb + (c4 * 2 + 1) * 384) = s1;
      }
#undef LOADU3
      nsum += __shfl_xor(nsum, 1);
      nsum += __shfl_xor(nsum, 2);
      nsum += __shfl_xor(nsum, 4);
      if ((tid & 7) == 0) {
        float* dst = (p == 0) ? nq : nk;
        atomicAdd(dst + (b * NH + h) * 24 + ch, nsum);
      }
    }
    __syncthreads();
  }

  // ---- MFMA: G += q-frags . k-frags (c>=24 lanes read the shared zero block)
  int l15 = lane & 15, gq = lane >> 4;
  f32x4 acc2[2][2];
#pragma unroll
  for (int ct = 0; ct < 2; ++ct)
#pragma unroll
    for (int dt = 0; dt < 2; ++dt) acc2[ct][dt] = (f32x4){0.f, 0.f, 0.f, 0.f};
#pragma unroll
  for (int t2 = 0; t2 < 2; ++t2) {
    int kt = w * 2 + t2;
    bf16x8 aq[2], bk[2];
#pragma unroll
    for (int ct = 0; ct < 2; ++ct) {
      int c = ct * 16 + l15;
      const unsigned char* qa =
          (c < 24) ? (lds + FB + kt * 1536 + gq * 384 + c * 16) : (lds + ZP);
      const unsigned char* ka =
          (c < 24) ? (lds + FB + 12288 + kt * 1536 + gq * 384 + c * 16) : (lds + ZP);
      aq[ct] = *(const bf16x8*)qa;
      bk[ct] = *(const bf16x8*)ka;
    }
#pragma unroll
    for (int ct = 0; ct < 2; ++ct)
#pragma unroll
      for (int dt = 0; dt < 2; ++dt)
        acc2[ct][dt] = __builtin_amdgcn_mfma_f32_16x16x32_bf16(aq[ct], bk[dt], acc2[ct][dt], 0, 0, 0);
  }
  float* gp = (float*)(lds + STG);
#pragma unroll
  for (int ct = 0; ct < 2; ++ct)
#pragma unroll
    for (int dt = 0; dt < 2; ++dt)
      *(f32x4*)(gp + (((w * 4 + ct * 2 + dt) * 64) + lane) * 4) = acc2[ct][dt];
  __syncthreads();
  float* Gb = G + (size_t)(b * NH + h) * 576;
#pragma unroll
  for (int ii = 0; ii < 3; ++ii) {
    int f = ii * 256 + tid;
    if (f < 576) {
      int c = f / 24, d = f % 24;
      int t4 = ((c >> 4) << 1) + (d >> 4);
      int lane16 = (d & 15) + (((c & 15) >> 2) << 4);
      int reg = c & 3;
      float s = 0.f;
#pragma unroll
      for (int w4 = 0; w4 < 4; ++w4)
        s += gp[((w4 * 4 + t4) * 64 + lane16) * 4 + reg];
      atomicAdd(Gb + f, s);
    }
  }
}

// ---------------- kdwv: depthwise 3x3 on v part -> vT slot-planar
__global__ __launch_bounds__(256) void kdwv(const unsigned short* __restrict__ src,
                                            const float* __restrict__ wdw,
                                            const float* __restrict__ bdw,
                                            unsigned char* __restrict__ vT) {
  __shared__ __align__(16) unsigned int smem[8 * 721];
  int wg = xcd_swz(blockIdx.x, gridDim.x);
  int cg = wg % 24, rt = (wg / 24) & 15, b = wg / 384;
  int y0 = rt * 8, chg0 = cg * 8;
  int tid = threadIdx.x;
  for (int i = tid; i < 5768; i += 256) smem[i] = 0;
  __syncthreads();
#pragma unroll
  for (int i = 0; i < 5; ++i) {
    int f = i * 256 + tid;
    int ch = f / 160, rem = f % 160;
    int r = rem >> 4, seg = rem & 15;
    int y = y0 - 1 + r;
    if (y >= 0 && y < HGT) {
      uint4 v = *(const uint4*)(src + ((size_t)(b * CC + chg0 + ch)) * HW + y * WID + seg * 8);
      unsigned int* dp = smem + ch * 721 + r * 72 + 4 + seg * 4;
      dp[0] = v.x; dp[1] = v.y; dp[2] = v.z; dp[3] = v.w;
    }
  }
  __syncthreads();
  int ch = tid >> 5, u = tid & 31;
  int row = u >> 2, xs = (u & 3) * 32;
  int gch = 384 + chg0 + ch;
  float wv[9];
#pragma unroll
  for (int j = 0; j < 9; ++j) wv[j] = wdw[gch * 9 + j];
  float bias = bdw[gch];
  float outv[32];
  const unsigned int* tb = smem + ch * 721;
#pragma unroll
  for (int g = 0; g < 4; ++g) {
    int x0 = xs + g * 8;
    float v[3][12];
#pragma unroll
    for (int dy = 0; dy < 3; ++dy) {
      const unsigned int* rp = tb + (row + dy) * 72 + ((x0 + 6) >> 1);
#pragma unroll
      for (int m = 0; m < 6; ++m) {
        unsigned int w2 = rp[m];
        v[dy][2 * m] = bf2f((unsigned short)(w2 & 0xffff));
        v[dy][2 * m + 1] = bf2f((unsigned short)(w2 >> 16));
      }
    }
#pragma unroll
    for (int j = 0; j < 8; ++j) {
      float a = bias;
#pragma unroll
      for (int dy = 0; dy < 3; ++dy)
#pragma unroll
        for (int dx = 0; dx < 3; ++dx)
          a += v[dy][j + dx + 1] * wv[dy * 3 + dx];
      outv[g * 8 + j] = a;
    }
  }
  __syncthreads();
  unsigned short* vt = (unsigned short*)smem;
#pragma unroll
  for (int g = 0; g < 4; ++g)
#pragma unroll
    for (int j = 0; j < 8; j += 2) {
      int x = xs + g * 8 + j;
      ((unsigned int*)smem)[ch * 512 + row * 64 + (x >> 1)] =
          pk2(outv[g * 8 + j], outv[g * 8 + j + 1]);
    }
  __syncthreads();
#pragma unroll
  for (int i = 0; i < 4; ++i) {
    int f = i * 256 + tid;
    int r = f >> 7, col = f & 127;
    unsigned int wvp[4];
#pragma unroll
    for (int e = 0; e < 4; ++e) {
      unsigned short a = vt[(2 * e) * 1024 + r * 128 + col];
      unsigned short bb = vt[(2 * e + 1) * 1024 + r * 128 + col];
      wvp[e] = (unsigned int)a | ((unsigned int)bb << 16);
    }
    uint4 st; st.x = wvp[0]; st.y = wvp[1]; st.z = wvp[2]; st.w = wvp[3];
    *(uint4*)(vT + (((size_t)(b * 24 + cg)) * HW + (size_t)(y0 + r) * WID + col) * 16) = st;
  }
}

// ---------------- kattn: softmax + fold w_proj -> W2[b] (bf16 swz rows)
__global__ __launch_bounds__(256) void kattn(const float* __restrict__ G,
                                             const float* __restrict__ nq,
                                             const float* __restrict__ nk,
                                             const float* __restrict__ temp,
                                             const float* __restrict__ wproj,
                                             unsigned char* __restrict__ W2) {
  __shared__ float attn[24][24];
  __shared__ float iq[24], ik[24];
  int bh = blockIdx.x;
  int h = bh & 7, b = bh >> 3;
  int tid = threadIdx.x;
  const float* Gb = G + (size_t)bh * 576;
  if (tid < 24) { float n = sqrtf(nq[bh * 24 + tid]); iq[tid] = 1.f / fmaxf(n, 1e-12f); }
  else if (tid < 48) { float n = sqrtf(nk[bh * 24 + tid - 24]); ik[tid - 24] = 1.f / fmaxf(n, 1e-12f); }
  __syncthreads();
  if (tid < 24) {
    float tmp = temp[h];
    float row[24];
    float mx = -1e30f;
#pragma unroll
    for (int d = 0; d < 24; ++d) {
      row[d] = Gb[tid * 24 + d] * iq[tid] * ik[d] * tmp;
      mx = fmaxf(mx, row[d]);
    }
    float sum = 0.f;
#pragma unroll
    for (int d = 0; d < 24; ++d) { float e = expf(row[d] - mx); row[d] = e; sum += e; }
    float inv = 1.f / sum;
#pragma unroll
    for (int d = 0; d < 24; ++d) attn[tid][d] = row[d] * inv;
  }
  __syncthreads();
  for (int i = 0; i < 18; ++i) {
    int f = tid + i * 256;
    if (f >= 4608) break;
    int oc = f / 24, d = f % 24;
    float s = 0.f;
#pragma unroll
    for (int c = 0; c < 24; ++c) s += wproj[oc * 192 + h * 24 + c] * attn[c][d];
    int gg = h * 24 + d;
    *(unsigned short*)(W2 + ((size_t)b * CC + oc) * 384 + ((gg * 2) ^ ((oc & 7) << 4))) = f2bf(s);
  }
}

// ---------------- kpos: pos = dwconv(gelu(dwconv(v,w1)),w2) ; v from vT slot-planar
__global__ __launch_bounds__(256) void kpos(const unsigned char* __restrict__ vT,
                                            const float* __restrict__ w1,
                                            const float* __restrict__ w2,
                                            unsigned short* __restrict__ pos) {
  __shared__ unsigned int vbuf[8 * 865];
  __shared__ unsigned int d1[8 * 721];
  int wg = xcd_swz(blockIdx.x, gridDim.x);
  int cg = wg % 24, rt = (wg / 24) & 15, b = wg / 384;
  int y0 = rt * 8, g0 = cg * 8;
  int tid = threadIdx.x;
  for (int i = tid; i < 6920; i += 256) vbuf[i] = 0;
  __syncthreads();
#pragma unroll
  for (int i = 0; i < 3; ++i) {
    int f = i * 256 + tid;
    int r = f >> 6, colp = f & 63;
    int y = y0 - 2 + r;
    if (y >= 0 && y < HGT) {
      const unsigned char* base = vT + (((size_t)(b * 24 + cg)) * HW + (size_t)y * WID + colp * 2) * 16;
      uint4 va = *(const uint4*)(base);
      uint4 vb2 = *(const uint4*)(base + 16);
      unsigned int la[4] = {va.x, va.y, va.z, va.w};
      unsigned int lb[4] = {vb2.x, vb2.y, vb2.z, vb2.w};
#pragma unroll
      for (int e = 0; e < 8; ++e) {
        unsigned int a16 = (la[e >> 1] >> ((e & 1) * 16)) & 0xffff;
        unsigned int b16 = (lb[e >> 1] >> ((e & 1) * 16)) & 0xffff;
        vbuf[e * 865 + r * 72 + colp + 4] = a16 | (b16 << 16);
      }
    }
  }
  __syncthreads();
  int ch = tid >> 5, u = tid & 31;
  {
    const float* wp = w1 + (g0 + ch) * 9;
    float wl[9];
#pragma unroll
    for (int j = 0; j < 9; ++j) wl[j] = wp[j];
    int x0 = u * 4;
    for (int rr = 0; rr < 10; ++rr) {
      int y = y0 - 1 + rr;
      unsigned int o0 = 0, o1 = 0;
      if (y >= 0 && y < HGT) {
        float v[3][8];
#pragma unroll
        for (int dy = 0; dy < 3; ++dy) {
          const unsigned int* rp = vbuf + ch * 865 + (rr + dy) * 72 + ((x0 + 6) >> 1);
#pragma unroll
          for (int m = 0; m < 4; ++m) {
            unsigned int w2r = rp[m];
            v[dy][2 * m] = bf2f((unsigned short)(w2r & 0xffff));
            v[dy][2 * m + 1] = bf2f((unsigned short)(w2r >> 16));
          }
        }
        float g4[4];
#pragma unroll
        for (int j = 0; j < 4; ++j) {
          float a = 0.f;
#pragma unroll
          for (int dy = 0; dy < 3; ++dy)
#pragma unroll
            for (int dx = 0; dx < 3; ++dx)
              a += v[dy][j + dx + 1] * wl[dy * 3 + dx];
          g4[j] = 0.5f * a * (1.f + erff(a * 0.70710678118f));
        }
        o0 = pk2(g4[0], g4[1]);
        o1 = pk2(g4[2], g4[3]);
      }
      unsigned int* dp = d1 + ch * 721 + rr * 72 + ((x0 + 8) >> 1);
      dp[0] = o0; dp[1] = o1;
    }
  }
  if (tid < 160) {
    int ech = tid / 20, rem = tid % 20;
    int rr = rem >> 1, side = rem & 1;
    int x = side ? 128 : -1;
    int y = y0 - 1 + rr;
    unsigned short val = 0;
    if (y >= 0 && y < HGT) {
      const float* wp = w1 + (g0 + ech) * 9;
      float a = 0.f;
      const unsigned short* vb16 = (const unsigned short*)(vbuf + ech * 865);
#pragma unroll
      for (int dy = 0; dy < 3; ++dy)
#pragma unroll
        for (int dx = 0; dx < 3; ++dx)
          a += bf2f(vb16[(rr + dy) * 144 + (x + dx + 7)]) * wp[dy * 3 + dx];
      val = f2bf(0.5f * a * (1.f + erff(a * 0.70710678118f)));
    }
    ((unsigned short*)(d1 + ech * 721))[rr * 144 + (x + 8)] = val;
  }
  __syncthreads();
  {
    const float* wp = w2 + (g0 + ch) * 9;
    float wl[9];
#pragma unroll
    for (int j = 0; j < 9; ++j) wl[j] = wp[j];
    int row = u >> 2, xs = (u & 3) * 32;
    size_t rb = ((size_t)(b * CC + g0 + ch)) * HW + (size_t)(y0 + row) * WID;
#pragma unroll
    for (int g = 0; g < 4; ++g) {
      int x0 = xs + g * 8;
      float v[3][12];
#pragma unroll
      for (int dy = 0; dy < 3; ++dy) {
        const unsigned int* rp = d1 + ch * 721 + (row + dy) * 72 + ((x0 + 6) >> 1);
#pragma unroll
        for (int m = 0; m < 6; ++m) {
          unsigned int w2r = rp[m];
          v[dy][2 * m] = bf2f((unsigned short)(w2r & 0xffff));
          v[dy][2 * m + 1] = bf2f((unsigned short)(w2r >> 16));
        }
      }
      uint4 st;
      float o[8];
#pragma unroll
      for (int j = 0; j < 8; ++j) {
        float a = 0.f;
#pragma unroll
        for (int dy = 0; dy < 3; ++dy)
#pragma unroll
          for (int dx = 0; dx < 3; ++dx)
            a += v[dy][j + dx + 1] * wl[dy * 3 + dx];
        o[j] = a;
      }
      st.x = pk2(o[0], o[1]); st.y = pk2(o[2], o[3]);
      st.z = pk2(o[4], o[5]); st.w = pk2(o[6], o[7]);
      *(uint4*)(pos + rb + x0) = st;
    }
  }
}

// ---------------- kproj v2: counted-vmcnt pipelined tiles; out = W2.v + bproj + pos
__global__ __launch_bounds__(256) void kproj(const unsigned char* __restrict__ vT,
                                             const unsigned char* __restrict__ W2,
                                             const float* __restrict__ bproj,
                                             const unsigned short* __restrict__ pos,
                                             float* __restrict__ out) {
  __shared__ __align__(16) unsigned char lds[73728];
  int wg = xcd_swz(blockIdx.x, gridDim.x);
  int ot = wg % 3; int rest = wg / 3; int grp = rest & 63; int b = rest >> 6;
  int tid = threadIdx.x;
  const unsigned char* gB = W2 + ((size_t)(b * 192 + ot * 64)) * 384;
#pragma unroll
  for (int i = 0; i < 6; ++i)
    gl_lds16(gB + i * 4096 + tid * 16, lds + 49152 + i * 4096 + tid * 16);
  const unsigned char* gA = vT + (size_t)b * 24 * HW * 16;
  int t0 = grp * 4;
  {
    int p0 = t0 * 64;
#pragma unroll
    for (int i = 0; i < 6; ++i) {
      int f = i * 256 + tid;
      gl_lds16(gA + (((size_t)(f >> 6)) * HW + p0 + (f & 63)) * 16, lds + f * 16);
    }
  }
  int lane = tid & 63, w = tid >> 6;
  int l15 = lane & 15, gq = lane >> 4;
  int pw = w * 16;
  float bias[4];
  size_t obase[4];
#pragma unroll
  for (int nf = 0; nf < 4; ++nf) {
    int oc = ot * 64 + nf * 16 + l15;
    bias[nf] = bproj[oc];
    obase[nf] = ((size_t)(b * 192 + oc)) * HW;
  }
  for (int it = 0; it < 4; ++it) {
    int tile = t0 + it;
    if (it == 0) { asm volatile("s_waitcnt vmcnt(0)" ::: "memory"); }
    else         { asm volatile("s_waitcnt vmcnt(4)" ::: "memory"); }
    __builtin_amdgcn_s_barrier();
    __builtin_amdgcn_sched_barrier(0);
    int nb = it & 1;
    int p = tile * 64 + pw + gq * 4;
    uint2 pv[4];
#pragma unroll
    for (int nf = 0; nf < 4; ++nf)
      pv[nf] = *(const uint2*)(pos + obase[nf] + p);
    if (it < 3) {
      int p1 = (tile + 1) * 64;
#pragma unroll
      for (int i = 0; i < 6; ++i) {
        int f = i * 256 + tid;
        gl_lds16(gA + (((size_t)(f >> 6)) * HW + p1 + (f & 63)) * 16,
                 lds + ((nb ^ 1) * 24576) + f * 16);
      }
    }
    __builtin_amdgcn_sched_barrier(0);   // pin prefetch before MFMA/stores
    f32x4 acc[4];
#pragma unroll
    for (int nf = 0; nf < 4; ++nf) acc[nf] = (f32x4){0.f, 0.f, 0.f, 0.f};
#pragma unroll
    for (int kk = 0; kk < 6; ++kk) {
      bf16x8 a = *(const bf16x8*)(lds + nb * 24576 + ((((kk * 4 + gq) << 6) + pw + l15) * 16));
      int cb = kk * 64 + gq * 16;
#pragma unroll
      for (int nf = 0; nf < 4; ++nf) {
        int r = nf * 16 + l15;
        bf16x8 bfr = *(const bf16x8*)(lds + 49152 + r * 384 + (cb ^ ((r & 7) << 4)));
        acc[nf] = __builtin_amdgcn_mfma_f32_16x16x32_bf16(a, bfr, acc[nf], 0, 0, 0);
      }
    }
#pragma unroll
    for (int nf = 0; nf < 4; ++nf) {
      float4 o;
      o.x = acc[nf][0] + bias[nf] + bf2f((unsigned short)(pv[nf].x & 0xffff));
      o.y = acc[nf][1] + bias[nf] + bf2f((unsigned short)(pv[nf].x >> 16));
      o.z = acc[nf][2] + bias[nf] + bf2f((unsigned short)(pv[nf].y & 0xffff));
      o.w = acc[nf][3] + bias[nf] + bf2f((unsigned short)(pv[nf].y >> 16));
      *(float4*)(out + obase[nf] + p) = o;
    }
  }
}

// ---------------- workspace layout ----------------
#define OFF_W   ((size_t)0)                    // 221184
#define OFF_G   ((size_t)221184)               // 147456
#define OFF_NQ  ((size_t)368640)               // 6144
#define OFF_NK  ((size_t)374784)               // 6144
#define OFF_W2  ((size_t)380928)               // 589824
#define OFF_QK  ((size_t)970752)               // 100663296 : qk 4px-unit; later pos
#define OFF_V   ((size_t)101634048)            // 50331648  : v planar
#define OFF_XT  ((size_t)151965696)            // 50331648  : vT slot-planar

extern "C" void kernel_launch(void* const* d_in, const int* in_sizes, int n_in,
                              void* d_out, int out_size, void* d_ws, size_t ws_size,
                              hipStream_t stream) {
  const float* x     = (const float*)d_in[0];
  const float* wqkv  = (const float*)d_in[1];
  const float* bqkv  = (const float*)d_in[2];
  const float* wdw   = (const float*)d_in[3];
  const float* bdw   = (const float*)d_in[4];
  const float* wproj = (const float*)d_in[5];
  const float* bproj = (const float*)d_in[6];
  const float* wpos1 = (const float*)d_in[7];
  const float* wpos2 = (const float*)d_in[8];
  const float* temp  = (const float*)d_in[9];
  unsigned char* ws = (unsigned char*)d_ws;

  kwprep<<<54, 256, 0, stream>>>(wqkv, ws + OFF_W, ws + OFF_G);
  kqkv<<<2048, 256, 0, stream>>>(x, ws + OFF_W, bqkv,
                                 (unsigned short*)(ws + OFF_V), ws + OFF_QK);
  kqk<<<4096, 256, 0, stream>>>(ws + OFF_QK, wdw, bdw, (float*)(ws + OFF_G),
                                (float*)(ws + OFF_NQ), (float*)(ws + OFF_NK));
  kdwv<<<3072, 256, 0, stream>>>((const unsigned short*)(ws + OFF_V), wdw, bdw,
                                 ws + OFF_XT);
  kattn<<<64, 256, 0, stream>>>((const float*)(ws + OFF_G), (const float*)(ws + OFF_NQ),
                                (const float*)(ws + OFF_NK), temp, wproj, ws + OFF_W2);
  kpos<<<3072, 256, 0, stream>>>(ws + OFF_XT, wpos1, wpos2,
                                 (unsigned short*)(ws + OFF_QK));
  kproj<<<1536, 256, 0, stream>>>(ws + OFF_XT, ws + OFF_W2, bproj,
                                  (const unsigned short*)(ws + OFF_QK), (float*)d_out);
}

// Round 12
// 284.309 us; speedup vs baseline: 1.0525x; 1.0525x over previous
//
#include <hip/hip_runtime.h>
#include <stdint.h>
#include <stddef.h>

#define NB 8
#define CC 192
#define C3 576
#define HGT 128
#define WID 128
#define HW 16384
#define NH 8
#define QKROW 49152   // per (part,b,y) row: 16 u-units * 192ch * 16B

typedef short bf16x8 __attribute__((ext_vector_type(8)));
typedef float f32x4 __attribute__((ext_vector_type(4)));

__device__ __forceinline__ unsigned short f2bf(float f) {
  unsigned int u = __float_as_uint(f);
  u += 0x7fffu + ((u >> 16) & 1u);
  return (unsigned short)(u >> 16);
}
__device__ __forceinline__ float bf2f(unsigned short h) {
  return __uint_as_float(((unsigned int)h) << 16);
}
__device__ __forceinline__ float bflo(unsigned int v) {
  return __uint_as_float(v << 16);
}
__device__ __forceinline__ float bfhi(unsigned int v) {
  return __uint_as_float(v & 0xffff0000u);
}
__device__ __forceinline__ unsigned int pk2(float a, float b) {
  return (unsigned int)f2bf(a) | ((unsigned int)f2bf(b) << 16);
}
__device__ __forceinline__ void gl_lds16(const void* g, void* l) {
  __builtin_amdgcn_global_load_lds(
      (const __attribute__((address_space(1))) unsigned int*)(uintptr_t)g,
      (__attribute__((address_space(3))) unsigned int*)(uint32_t)(uintptr_t)l,
      16, 0, 0);
}
__device__ __forceinline__ int xcd_swz(int g, int n) {
  return (g & 7) * (n >> 3) + (g >> 3);
}

// ---------------- kwprep: w_qkv -> bf16 swizzled rows; also zeroes G/nq/nk (159744 B)
__global__ void kwprep(const float* __restrict__ wq, unsigned char* __restrict__ wb,
                       unsigned char* __restrict__ zero_region) {
  int f = blockIdx.x * 256 + threadIdx.x;
  if (f < 9984) *(uint4*)(zero_region + (size_t)f * 16) = (uint4){0, 0, 0, 0};
  if (f >= C3 * 24) return;
  int oc = f / 24, s = f % 24;
  unsigned int wv[4];
#pragma unroll
  for (int j = 0; j < 4; ++j)
    wv[j] = pk2(wq[oc * 192 + s * 8 + 2 * j], wq[oc * 192 + s * 8 + 2 * j + 1]);
  uint4 st; st.x = wv[0]; st.y = wv[1]; st.z = wv[2]; st.w = wv[3];
  *(uint4*)(wb + (size_t)oc * 384 + ((s ^ (oc & 7)) * 16)) = st;
}

// ---------------- kqkv v3: fused cast/transpose + qkv conv1x1, 52KB LDS, 3 blocks/CU
// 18 half-tile iterations (2 oc-frags each); B half dbuf 2x12KB; TR 4KB; vmcnt(1).
__global__ __launch_bounds__(256) void kqkv(const float* __restrict__ x,
                                            const unsigned char* __restrict__ wb,
                                            const float* __restrict__ bqkv,
                                            unsigned short* __restrict__ vout,
                                            unsigned char* __restrict__ qkout) {
  __shared__ __align__(16) unsigned char lds[53248];
  const int ABF = 0;       // A bf16 [24 s][64 p][16B] = 24576
  const int BB  = 24576;   // B half-tile dbuf 2 x 12288 (prologue: x-chunk staging)
  const int TR  = 49152;   // 4KB transpose buffer
  int wg = xcd_swz(blockIdx.x, gridDim.x);
  int t = wg & 255, b = wg >> 8;
  int p0 = t * 64;
  int tid = threadIdx.x;
  const unsigned char* gx = (const unsigned char*)(x + (size_t)b * CC * HW + p0);

  // ---- prologue: stage+repack x in 2 chunks of 96 channels through BB region
  int p = tid & 63, sg = tid >> 6;
#pragma unroll
  for (int ck = 0; ck < 2; ++ck) {
#pragma unroll
    for (int i = 0; i < 6; ++i) {
      int f = i * 256 + tid;
      int ch = ck * 96 + (f >> 4), seg = f & 15;
      gl_lds16(gx + ((size_t)ch * HW + seg * 4) * 4, lds + BB + f * 16);
    }
    asm volatile("s_waitcnt vmcnt(0)" ::: "memory");
    __syncthreads();
    const float* lx = (const float*)(lds + BB);
#pragma unroll
    for (int s3 = 0; s3 < 3; ++s3) {
      int s = sg * 3 + s3;
      unsigned int wv[4];
#pragma unroll
      for (int j = 0; j < 4; ++j)
        wv[j] = pk2(lx[(s * 8 + 2 * j) * 64 + p], lx[(s * 8 + 2 * j + 1) * 64 + p]);
      uint4 st; st.x = wv[0]; st.y = wv[1]; st.z = wv[2]; st.w = wv[3];
      *(uint4*)(lds + ABF + ((ck * 12 + s) * 64 + p) * 16) = st;
    }
    __syncthreads();
  }
  // ---- issue B half 0 (ot=0, hh=0)
#pragma unroll
  for (int i = 0; i < 3; ++i)
    gl_lds16(wb + i * 4096 + tid * 16, lds + BB + i * 4096 + tid * 16);

  int lane = tid & 63, w = tid >> 6;
  int l15 = lane & 15, gq = lane >> 4;
  int pw = w * 16;
  int y = t >> 1, xh = (t & 1) * 8;
  int unitw = w * 2 + (gq >> 1);
  int sub8 = (gq & 1) * 8;
  int s4 = w * 4 + gq;
  int tc = tid & 31, tu = tid >> 5;    // q TR-read mapping
  int vcv = tid >> 3, vx = tid & 7;    // v TR-read mapping

  for (int j = 0; j < 18; ++j) {
    int ot = j >> 1, hh = j & 1, cur = j & 1;
    // robust counted wait: exactly one global store issued after the newest
    // B-half prefetch, so vmcnt(1) guarantees that prefetch has landed.
    if (j == 0) { asm volatile("s_waitcnt vmcnt(0)" ::: "memory"); }
    else        { asm volatile("s_waitcnt vmcnt(1)" ::: "memory"); }
    __builtin_amdgcn_s_barrier();
    __builtin_amdgcn_sched_barrier(0);
    float bias0 = bqkv[ot * 64 + hh * 32 + l15];
    float bias1 = bqkv[ot * 64 + hh * 32 + 16 + l15];
    if (j < 17) {
      int jn = j + 1;
      const unsigned char* gB = wb + (size_t)(jn >> 1) * 24576 + (jn & 1) * 12288;
#pragma unroll
      for (int i = 0; i < 3; ++i)
        gl_lds16(gB + i * 4096 + tid * 16, lds + BB + (cur ^ 1) * 12288 + i * 4096 + tid * 16);
    }
    f32x4 acc[2];
    acc[0] = (f32x4){0.f, 0.f, 0.f, 0.f};
    acc[1] = (f32x4){0.f, 0.f, 0.f, 0.f};
#pragma unroll
    for (int kk = 0; kk < 6; ++kk) {
      bf16x8 a = *(const bf16x8*)(lds + ABF + (((kk * 4 + gq) * 64) + pw + l15) * 16);
      int cb = kk * 64 + gq * 16;
#pragma unroll
      for (int nf2 = 0; nf2 < 2; ++nf2) {
        int r2 = nf2 * 16 + l15;
        bf16x8 bfr = *(const bf16x8*)(lds + BB + cur * 12288 + r2 * 384 + (cb ^ ((r2 & 7) << 4)));
        acc[nf2] = __builtin_amdgcn_mfma_f32_16x16x32_bf16(a, bfr, acc[nf2], 0, 0, 0);
      }
    }
    bool isq = (ot < 6);
    if (isq) {
#pragma unroll
      for (int nf2 = 0; nf2 < 2; ++nf2) {
        int c = nf2 * 16 + l15;
        float bs = nf2 ? bias1 : bias0;
        uint2 st;
        st.x = pk2(acc[nf2][0] + bs, acc[nf2][1] + bs);
        st.y = pk2(acc[nf2][2] + bs, acc[nf2][3] + bs);
        *(uint2*)(lds + TR + c * 128 + ((unitw ^ (c & 7)) * 16) + sub8) = st;
      }
    } else {
#pragma unroll
      for (int nf2 = 0; nf2 < 2; ++nf2) {
        int c = nf2 * 16 + l15;
        float bs = nf2 ? bias1 : bias0;
        uint2 st;
        st.x = pk2(acc[nf2][0] + bs, acc[nf2][1] + bs);
        st.y = pk2(acc[nf2][2] + bs, acc[nf2][3] + bs);
        *(uint2*)(lds + TR + c * 128 + ((s4 ^ (c & 15)) * 8)) = st;
      }
    }
    asm volatile("s_waitcnt lgkmcnt(0)" ::: "memory");
    __builtin_amdgcn_s_barrier();
    __builtin_amdgcn_sched_barrier(0);
    if (isq) {
      int part = ot / 3, cm = (ot % 3) * 64 + hh * 32 + tc;
      uint4 v0 = *(const uint4*)(lds + TR + tc * 128 + ((tu ^ (tc & 7)) * 16));
      *(uint4*)(qkout + ((size_t)((part * 8 + b) * 128 + y)) * QKROW +
                (xh + tu) * 3072 + cm * 16) = v0;
    } else {
      uint2 q0 = *(const uint2*)(lds + TR + vcv * 128 + (((2 * vx) ^ (vcv & 15)) * 8));
      uint2 q1 = *(const uint2*)(lds + TR + vcv * 128 + (((2 * vx + 1) ^ (vcv & 15)) * 8));
      uint4 s0; s0.x = q0.x; s0.y = q0.y; s0.z = q1.x; s0.w = q1.y;
      *(uint4*)(vout + ((size_t)(b * CC + (ot - 6) * 64 + hh * 32 + vcv)) * HW +
                p0 + vx * 8) = s0;
    }
  }
}

// ---------------- kqk v3: dwconv(q,k) + Gram + norms, 2-row bands, 3 blocks/CU
__global__ __launch_bounds__(256) void kqk(const unsigned char* __restrict__ qk,
                                           const float* __restrict__ wdw,
                                           const float* __restrict__ bdw,
                                           float* __restrict__ G,
                                           float* __restrict__ nq,
                                           float* __restrict__ nk) {
  __shared__ __align__(16) unsigned char lds[49168];
  const int FB = 0;
  const int ZP = 24576;
  const int STG = 24592;
  int wg = xcd_swz(blockIdx.x, gridDim.x);
  int band = wg & 63, h = (wg >> 6) & 7, b = wg >> 9;
  int y0 = band * 2;
  int tid = threadIdx.x;
  if (tid == 0) *(uint4*)(lds + ZP) = (uint4){0, 0, 0, 0};

  int lane = tid & 63, w = tid >> 6;
  int ch = tid >> 3, row = (tid >> 2) & 1, qt = tid & 3;
  int u0 = qt * 4;

#pragma unroll
  for (int p = 0; p < 2; ++p) {
#pragma unroll
    for (int i = 0; i < 6; ++i) {
      int f = i * 256 + tid;
      int r = f / 384, unit = f % 384;
      int uc = unit / 24, cs = unit % 24;
      int yy = y0 - 1 + r;
      if (yy >= 0 && yy < HGT)
        gl_lds16(qk + ((size_t)((p * 8 + b) * 128 + yy)) * QKROW + uc * 3072 + (h * 24 + cs) * 16,
                 lds + STG + f * 16);
      else
        *(uint4*)(lds + STG + f * 16) = (uint4){0, 0, 0, 0};
    }
    asm volatile("s_waitcnt vmcnt(0)" ::: "memory");
    __syncthreads();
    if (tid < 192) {
      int gc = p * 192 + h * 24 + ch;
      float wv[9];
#pragma unroll
      for (int j = 0; j < 9; ++j) wv[j] = wdw[gc * 9 + j];
      float bias = bdw[gc];
      const unsigned char* sbase = lds + STG + ch * 16;
      unsigned char* fb = lds + FB + p * 12288 + (row * 4 + qt) * 1536 + ch * 16;
      unsigned int W[3][16];
#define LOADU3(dy_, m_, u_) { \
    uint4 tt = ((u_) >= 0 && (u_) < 16) \
        ? *(const uint4*)(sbase + (row + (dy_)) * 6144 + (u_) * 384) \
        : (uint4){0, 0, 0, 0}; \
    W[dy_][(m_) * 4 + 0] = tt.x; W[dy_][(m_) * 4 + 1] = tt.y; \
    W[dy_][(m_) * 4 + 2] = tt.z; W[dy_][(m_) * 4 + 3] = tt.w; }
#pragma unroll
      for (int dy = 0; dy < 3; ++dy) {
#pragma unroll
        for (int m = 0; m < 4; ++m) { LOADU3(dy, m, u0 - 1 + m); }
      }
      float nsum = 0.f;
#pragma unroll
      for (int c4 = 0; c4 < 2; ++c4) {
        if (c4 > 0) {
#pragma unroll
          for (int dy = 0; dy < 3; ++dy) {
#pragma unroll
            for (int e = 0; e < 8; ++e) W[dy][e] = W[dy][8 + e];
            LOADU3(dy, 2, u0 + 3);
            LOADU3(dy, 3, u0 + 4);
          }
        }
        float acc[16];
#pragma unroll
        for (int j = 0; j < 16; ++j) acc[j] = bias;
#pragma unroll
        for (int dy = 0; dy < 3; ++dy) {
          float f[18];
#pragma unroll
          for (int t2 = 0; t2 < 18; ++t2) {
            int rel = 7 + t2;
            unsigned int v = W[dy][rel >> 1];
            f[t2] = (rel & 1) ? bfhi(v) : bflo(v);
          }
#pragma unroll
          for (int j = 0; j < 16; ++j)
            acc[j] += f[j] * wv[dy * 3] + f[j + 1] * wv[dy * 3 + 1] + f[j + 2] * wv[dy * 3 + 2];
        }
#pragma unroll
        for (int j = 0; j < 16; ++j) nsum += acc[j] * acc[j];
        unsigned int pk[8];
#pragma unroll
        for (int e = 0; e < 8; ++e) pk[e] = pk2(acc[2 * e], acc[2 * e + 1]);
        uint4 s0; s0.x = pk[0]; s0.y = pk[1]; s0.z = pk[2]; s0.w = pk[3];
        uint4 s1; s1.x = pk[4]; s1.y = pk[5]; s1.z = pk[6]; s1.w = pk[7];
        *(uint4*)(fb + (c4 * 2) * 384) = s0;
        *(uint4*)(fb + (c4 * 2 + 1) * 384) = s1;
      }
#undef LOADU3
      nsum += __shfl_xor(nsum, 1);
      nsum += __shfl_xor(nsum, 2);
      nsum += __shfl_xor(nsum, 4);
      if ((tid & 7) == 0) {
        float* dst = (p == 0) ? nq : nk;
        atomicAdd(dst + (b * NH + h) * 24 + ch, nsum);
      }
    }
    __syncthreads();
  }

  int l15 = lane & 15, gq = lane >> 4;
  f32x4 acc2[2][2];
#pragma unroll
  for (int ct = 0; ct < 2; ++ct)
#pragma unroll
    for (int dt = 0; dt < 2; ++dt) acc2[ct][dt] = (f32x4){0.f, 0.f, 0.f, 0.f};
#pragma unroll
  for (int t2 = 0; t2 < 2; ++t2) {
    int kt = w * 2 + t2;
    bf16x8 aq[2], bk[2];
#pragma unroll
    for (int ct = 0; ct < 2; ++ct) {
      int c = ct * 16 + l15;
      const unsigned char* qa =
          (c < 24) ? (lds + FB + kt * 1536 + gq * 384 + c * 16) : (lds + ZP);
      const unsigned char* ka =
          (c < 24) ? (lds + FB + 12288 + kt * 1536 + gq * 384 + c * 16) : (lds + ZP);
      aq[ct] = *(const bf16x8*)qa;
      bk[ct] = *(const bf16x8*)ka;
    }
#pragma unroll
    for (int ct = 0; ct < 2; ++ct)
#pragma unroll
      for (int dt = 0; dt < 2; ++dt)
        acc2[ct][dt] = __builtin_amdgcn_mfma_f32_16x16x32_bf16(aq[ct], bk[dt], acc2[ct][dt], 0, 0, 0);
  }
  float* gp = (float*)(lds + STG);
#pragma unroll
  for (int ct = 0; ct < 2; ++ct)
#pragma unroll
    for (int dt = 0; dt < 2; ++dt)
      *(f32x4*)(gp + (((w * 4 + ct * 2 + dt) * 64) + lane) * 4) = acc2[ct][dt];
  __syncthreads();
  float* Gb = G + (size_t)(b * NH + h) * 576;
#pragma unroll
  for (int ii = 0; ii < 3; ++ii) {
    int f = ii * 256 + tid;
    if (f < 576) {
      int c = f / 24, d = f % 24;
      int t4 = ((c >> 4) << 1) + (d >> 4);
      int lane16 = (d & 15) + (((c & 15) >> 2) << 4);
      int reg = c & 3;
      float s = 0.f;
#pragma unroll
      for (int w4 = 0; w4 < 4; ++w4)
        s += gp[((w4 * 4 + t4) * 64 + lane16) * 4 + reg];
      atomicAdd(Gb + f, s);
    }
  }
}

// ---------------- kdwv: depthwise 3x3 on v part -> vT slot-planar
__global__ __launch_bounds__(256) void kdwv(const unsigned short* __restrict__ src,
                                            const float* __restrict__ wdw,
                                            const float* __restrict__ bdw,
                                            unsigned char* __restrict__ vT) {
  __shared__ __align__(16) unsigned int smem[8 * 721];
  int wg = xcd_swz(blockIdx.x, gridDim.x);
  int cg = wg % 24, rt = (wg / 24) & 15, b = wg / 384;
  int y0 = rt * 8, chg0 = cg * 8;
  int tid = threadIdx.x;
  for (int i = tid; i < 5768; i += 256) smem[i] = 0;
  __syncthreads();
#pragma unroll
  for (int i = 0; i < 5; ++i) {
    int f = i * 256 + tid;
    int ch = f / 160, rem = f % 160;
    int r = rem >> 4, seg = rem & 15;
    int y = y0 - 1 + r;
    if (y >= 0 && y < HGT) {
      uint4 v = *(const uint4*)(src + ((size_t)(b * CC + chg0 + ch)) * HW + y * WID + seg * 8);
      unsigned int* dp = smem + ch * 721 + r * 72 + 4 + seg * 4;
      dp[0] = v.x; dp[1] = v.y; dp[2] = v.z; dp[3] = v.w;
    }
  }
  __syncthreads();
  int ch = tid >> 5, u = tid & 31;
  int row = u >> 2, xs = (u & 3) * 32;
  int gch = 384 + chg0 + ch;
  float wv[9];
#pragma unroll
  for (int j = 0; j < 9; ++j) wv[j] = wdw[gch * 9 + j];
  float bias = bdw[gch];
  float outv[32];
  const unsigned int* tb = smem + ch * 721;
#pragma unroll
  for (int g = 0; g < 4; ++g) {
    int x0 = xs + g * 8;
    float v[3][12];
#pragma unroll
    for (int dy = 0; dy < 3; ++dy) {
      const unsigned int* rp = tb + (row + dy) * 72 + ((x0 + 6) >> 1);
#pragma unroll
      for (int m = 0; m < 6; ++m) {
        unsigned int w2 = rp[m];
        v[dy][2 * m] = bf2f((unsigned short)(w2 & 0xffff));
        v[dy][2 * m + 1] = bf2f((unsigned short)(w2 >> 16));
      }
    }
#pragma unroll
    for (int j = 0; j < 8; ++j) {
      float a = bias;
#pragma unroll
      for (int dy = 0; dy < 3; ++dy)
#pragma unroll
        for (int dx = 0; dx < 3; ++dx)
          a += v[dy][j + dx + 1] * wv[dy * 3 + dx];
      outv[g * 8 + j] = a;
    }
  }
  __syncthreads();
  unsigned short* vt = (unsigned short*)smem;
#pragma unroll
  for (int g = 0; g < 4; ++g)
#pragma unroll
    for (int j = 0; j < 8; j += 2) {
      int x = xs + g * 8 + j;
      ((unsigned int*)smem)[ch * 512 + row * 64 + (x >> 1)] =
          pk2(outv[g * 8 + j], outv[g * 8 + j + 1]);
    }
  __syncthreads();
#pragma unroll
  for (int i = 0; i < 4; ++i) {
    int f = i * 256 + tid;
    int r = f >> 7, col = f & 127;
    unsigned int wvp[4];
#pragma unroll
    for (int e = 0; e < 4; ++e) {
      unsigned short a = vt[(2 * e) * 1024 + r * 128 + col];
      unsigned short bb = vt[(2 * e + 1) * 1024 + r * 128 + col];
      wvp[e] = (unsigned int)a | ((unsigned int)bb << 16);
    }
    uint4 st; st.x = wvp[0]; st.y = wvp[1]; st.z = wvp[2]; st.w = wvp[3];
    *(uint4*)(vT + (((size_t)(b * 24 + cg)) * HW + (size_t)(y0 + r) * WID + col) * 16) = st;
  }
}

// ---------------- kattn: softmax + fold w_proj -> W2[b] (bf16 swz rows)
__global__ __launch_bounds__(256) void kattn(const float* __restrict__ G,
                                             const float* __restrict__ nq,
                                             const float* __restrict__ nk,
                                             const float* __restrict__ temp,
                                             const float* __restrict__ wproj,
                                             unsigned char* __restrict__ W2) {
  __shared__ float attn[24][24];
  __shared__ float iq[24], ik[24];
  int bh = blockIdx.x;
  int h = bh & 7, b = bh >> 3;
  int tid = threadIdx.x;
  const float* Gb = G + (size_t)bh * 576;
  if (tid < 24) { float n = sqrtf(nq[bh * 24 + tid]); iq[tid] = 1.f / fmaxf(n, 1e-12f); }
  else if (tid < 48) { float n = sqrtf(nk[bh * 24 + tid - 24]); ik[tid - 24] = 1.f / fmaxf(n, 1e-12f); }
  __syncthreads();
  if (tid < 24) {
    float tmp = temp[h];
    float row[24];
    float mx = -1e30f;
#pragma unroll
    for (int d = 0; d < 24; ++d) {
      row[d] = Gb[tid * 24 + d] * iq[tid] * ik[d] * tmp;
      mx = fmaxf(mx, row[d]);
    }
    float sum = 0.f;
#pragma unroll
    for (int d = 0; d < 24; ++d) { float e = expf(row[d] - mx); row[d] = e; sum += e; }
    float inv = 1.f / sum;
#pragma unroll
    for (int d = 0; d < 24; ++d) attn[tid][d] = row[d] * inv;
  }
  __syncthreads();
  for (int i = 0; i < 18; ++i) {
    int f = tid + i * 256;
    if (f >= 4608) break;
    int oc = f / 24, d = f % 24;
    float s = 0.f;
#pragma unroll
    for (int c = 0; c < 24; ++c) s += wproj[oc * 192 + h * 24 + c] * attn[c][d];
    int gg = h * 24 + d;
    *(unsigned short*)(W2 + ((size_t)b * CC + oc) * 384 + ((gg * 2) ^ ((oc & 7) << 4))) = f2bf(s);
  }
}

// ---------------- kpos: pos = dwconv(gelu(dwconv(v,w1)),w2) ; v from vT slot-planar
__global__ __launch_bounds__(256) void kpos(const unsigned char* __restrict__ vT,
                                            const float* __restrict__ w1,
                                            const float* __restrict__ w2,
                                            unsigned short* __restrict__ pos) {
  __shared__ unsigned int vbuf[8 * 865];
  __shared__ unsigned int d1[8 * 721];
  int wg = xcd_swz(blockIdx.x, gridDim.x);
  int cg = wg % 24, rt = (wg / 24) & 15, b = wg / 384;
  int y0 = rt * 8, g0 = cg * 8;
  int tid = threadIdx.x;
  for (int i = tid; i < 6920; i += 256) vbuf[i] = 0;
  __syncthreads();
#pragma unroll
  for (int i = 0; i < 3; ++i) {
    int f = i * 256 + tid;
    int r = f >> 6, colp = f & 63;
    int y = y0 - 2 + r;
    if (y >= 0 && y < HGT) {
      const unsigned char* base = vT + (((size_t)(b * 24 + cg)) * HW + (size_t)y * WID + colp * 2) * 16;
      uint4 va = *(const uint4*)(base);
      uint4 vb2 = *(const uint4*)(base + 16);
      unsigned int la[4] = {va.x, va.y, va.z, va.w};
      unsigned int lb[4] = {vb2.x, vb2.y, vb2.z, vb2.w};
#pragma unroll
      for (int e = 0; e < 8; ++e) {
        unsigned int a16 = (la[e >> 1] >> ((e & 1) * 16)) & 0xffff;
        unsigned int b16 = (lb[e >> 1] >> ((e & 1) * 16)) & 0xffff;
        vbuf[e * 865 + r * 72 + colp + 4] = a16 | (b16 << 16);
      }
    }
  }
  __syncthreads();
  int ch = tid >> 5, u = tid & 31;
  {
    const float* wp = w1 + (g0 + ch) * 9;
    float wl[9];
#pragma unroll
    for (int j = 0; j < 9; ++j) wl[j] = wp[j];
    int x0 = u * 4;
    for (int rr = 0; rr < 10; ++rr) {
      int y = y0 - 1 + rr;
      unsigned int o0 = 0, o1 = 0;
      if (y >= 0 && y < HGT) {
        float v[3][8];
#pragma unroll
        for (int dy = 0; dy < 3; ++dy) {
          const unsigned int* rp = vbuf + ch * 865 + (rr + dy) * 72 + ((x0 + 6) >> 1);
#pragma unroll
          for (int m = 0; m < 4; ++m) {
            unsigned int w2r = rp[m];
            v[dy][2 * m] = bf2f((unsigned short)(w2r & 0xffff));
            v[dy][2 * m + 1] = bf2f((unsigned short)(w2r >> 16));
          }
        }
        float g4[4];
#pragma unroll
        for (int j = 0; j < 4; ++j) {
          float a = 0.f;
#pragma unroll
          for (int dy = 0; dy < 3; ++dy)
#pragma unroll
            for (int dx = 0; dx < 3; ++dx)
              a += v[dy][j + dx + 1] * wl[dy * 3 + dx];
          g4[j] = 0.5f * a * (1.f + erff(a * 0.70710678118f));
        }
        o0 = pk2(g4[0], g4[1]);
        o1 = pk2(g4[2], g4[3]);
      }
      unsigned int* dp = d1 + ch * 721 + rr * 72 + ((x0 + 8) >> 1);
      dp[0] = o0; dp[1] = o1;
    }
  }
  if (tid < 160) {
    int ech = tid / 20, rem = tid % 20;
    int rr = rem >> 1, side = rem & 1;
    int x = side ? 128 : -1;
    int y = y0 - 1 + rr;
    unsigned short val = 0;
    if (y >= 0 && y < HGT) {
      const float* wp = w1 + (g0 + ech) * 9;
      float a = 0.f;
      const unsigned short* vb16 = (const unsigned short*)(vbuf + ech * 865);
#pragma unroll
      for (int dy = 0; dy < 3; ++dy)
#pragma unroll
        for (int dx = 0; dx < 3; ++dx)
          a += bf2f(vb16[(rr + dy) * 144 + (x + dx + 7)]) * wp[dy * 3 + dx];
      val = f2bf(0.5f * a * (1.f + erff(a * 0.70710678118f)));
    }
    ((unsigned short*)(d1 + ech * 721))[rr * 144 + (x + 8)] = val;
  }
  __syncthreads();
  {
    const float* wp = w2 + (g0 + ch) * 9;
    float wl[9];
#pragma unroll
    for (int j = 0; j < 9; ++j) wl[j] = wp[j];
    int row = u >> 2, xs = (u & 3) * 32;
    size_t rb = ((size_t)(b * CC + g0 + ch)) * HW + (size_t)(y0 + row) * WID;
#pragma unroll
    for (int g = 0; g < 4; ++g) {
      int x0 = xs + g * 8;
      float v[3][12];
#pragma unroll
      for (int dy = 0; dy < 3; ++dy) {
        const unsigned int* rp = d1 + ch * 721 + (row + dy) * 72 + ((x0 + 6) >> 1);
#pragma unroll
        for (int m = 0; m < 6; ++m) {
          unsigned int w2r = rp[m];
          v[dy][2 * m] = bf2f((unsigned short)(w2r & 0xffff));
          v[dy][2 * m + 1] = bf2f((unsigned short)(w2r >> 16));
        }
      }
      uint4 st;
      float o[8];
#pragma unroll
      for (int j = 0; j < 8; ++j) {
        float a = 0.f;
#pragma unroll
        for (int dy = 0; dy < 3; ++dy)
#pragma unroll
          for (int dx = 0; dx < 3; ++dx)
            a += v[dy][j + dx + 1] * wl[dy * 3 + dx];
        o[j] = a;
      }
      st.x = pk2(o[0], o[1]); st.y = pk2(o[2], o[3]);
      st.z = pk2(o[4], o[5]); st.w = pk2(o[6], o[7]);
      *(uint4*)(pos + rb + x0) = st;
    }
  }
}

// ---------------- kproj v2: counted-vmcnt pipelined tiles; out = W2.v + bproj + pos
__global__ __launch_bounds__(256) void kproj(const unsigned char* __restrict__ vT,
                                             const unsigned char* __restrict__ W2,
                                             const float* __restrict__ bproj,
                                             const unsigned short* __restrict__ pos,
                                             float* __restrict__ out) {
  __shared__ __align__(16) unsigned char lds[73728];
  int wg = xcd_swz(blockIdx.x, gridDim.x);
  int ot = wg % 3; int rest = wg / 3; int grp = rest & 63; int b = rest >> 6;
  int tid = threadIdx.x;
  const unsigned char* gB = W2 + ((size_t)(b * 192 + ot * 64)) * 384;
#pragma unroll
  for (int i = 0; i < 6; ++i)
    gl_lds16(gB + i * 4096 + tid * 16, lds + 49152 + i * 4096 + tid * 16);
  const unsigned char* gA = vT + (size_t)b * 24 * HW * 16;
  int t0 = grp * 4;
  {
    int p0 = t0 * 64;
#pragma unroll
    for (int i = 0; i < 6; ++i) {
      int f = i * 256 + tid;
      gl_lds16(gA + (((size_t)(f >> 6)) * HW + p0 + (f & 63)) * 16, lds + f * 16);
    }
  }
  int lane = tid & 63, w = tid >> 6;
  int l15 = lane & 15, gq = lane >> 4;
  int pw = w * 16;
  float bias[4];
  size_t obase[4];
#pragma unroll
  for (int nf = 0; nf < 4; ++nf) {
    int oc = ot * 64 + nf * 16 + l15;
    bias[nf] = bproj[oc];
    obase[nf] = ((size_t)(b * 192 + oc)) * HW;
  }
  for (int it = 0; it < 4; ++it) {
    int tile = t0 + it;
    if (it == 0) { asm volatile("s_waitcnt vmcnt(0)" ::: "memory"); }
    else         { asm volatile("s_waitcnt vmcnt(4)" ::: "memory"); }
    __builtin_amdgcn_s_barrier();
    __builtin_amdgcn_sched_barrier(0);
    int nb = it & 1;
    int p = tile * 64 + pw + gq * 4;
    uint2 pv[4];
#pragma unroll
    for (int nf = 0; nf < 4; ++nf)
      pv[nf] = *(const uint2*)(pos + obase[nf] + p);
    if (it < 3) {
      int p1 = (tile + 1) * 64;
#pragma unroll
      for (int i = 0; i < 6; ++i) {
        int f = i * 256 + tid;
        gl_lds16(gA + (((size_t)(f >> 6)) * HW + p1 + (f & 63)) * 16,
                 lds + ((nb ^ 1) * 24576) + f * 16);
      }
    }
    __builtin_amdgcn_sched_barrier(0);   // pin prefetch before MFMA/stores
    f32x4 acc[4];
#pragma unroll
    for (int nf = 0; nf < 4; ++nf) acc[nf] = (f32x4){0.f, 0.f, 0.f, 0.f};
#pragma unroll
    for (int kk = 0; kk < 6; ++kk) {
      bf16x8 a = *(const bf16x8*)(lds + nb * 24576 + ((((kk * 4 + gq) << 6) + pw + l15) * 16));
      int cb = kk * 64 + gq * 16;
#pragma unroll
      for (int nf = 0; nf < 4; ++nf) {
        int r = nf * 16 + l15;
        bf16x8 bfr = *(const bf16x8*)(lds + 49152 + r * 384 + (cb ^ ((r & 7) << 4)));
        acc[nf] = __builtin_amdgcn_mfma_f32_16x16x32_bf16(a, bfr, acc[nf], 0, 0, 0);
      }
    }
#pragma unroll
    for (int nf = 0; nf < 4; ++nf) {
      float4 o;
      o.x = acc[nf][0] + bias[nf] + bf2f((unsigned short)(pv[nf].x & 0xffff));
      o.y = acc[nf][1] + bias[nf] + bf2f((unsigned short)(pv[nf].x >> 16));
      o.z = acc[nf][2] + bias[nf] + bf2f((unsigned short)(pv[nf].y & 0xffff));
      o.w = acc[nf][3] + bias[nf] + bf2f((unsigned short)(pv[nf].y >> 16));
      *(float4*)(out + obase[nf] + p) = o;
    }
  }
}

// ---------------- workspace layout ----------------
#define OFF_W   ((size_t)0)                    // 221184
#define OFF_G   ((size_t)221184)               // 147456
#define OFF_NQ  ((size_t)368640)               // 6144
#define OFF_NK  ((size_t)374784)               // 6144
#define OFF_W2  ((size_t)380928)               // 589824
#define OFF_QK  ((size_t)970752)               // 100663296 : qk u-major; later pos
#define OFF_V   ((size_t)101634048)            // 50331648  : v planar
#define OFF_XT  ((size_t)151965696)            // 50331648  : vT slot-planar

extern "C" void kernel_launch(void* const* d_in, const int* in_sizes, int n_in,
                              void* d_out, int out_size, void* d_ws, size_t ws_size,
                              hipStream_t stream) {
  const float* x     = (const float*)d_in[0];
  const float* wqkv  = (const float*)d_in[1];
  const float* bqkv  = (const float*)d_in[2];
  const float* wdw   = (const float*)d_in[3];
  const float* bdw   = (const float*)d_in[4];
  const float* wproj = (const float*)d_in[5];
  const float* bproj = (const float*)d_in[6];
  const float* wpos1 = (const float*)d_in[7];
  const float* wpos2 = (const float*)d_in[8];
  const float* temp  = (const float*)d_in[9];
  unsigned char* ws = (unsigned char*)d_ws;

  kwprep<<<54, 256, 0, stream>>>(wqkv, ws + OFF_W, ws + OFF_G);
  kqkv<<<2048, 256, 0, stream>>>(x, ws + OFF_W, bqkv,
                                 (unsigned short*)(ws + OFF_V), ws + OFF_QK);
  kqk<<<4096, 256, 0, stream>>>(ws + OFF_QK, wdw, bdw, (float*)(ws + OFF_G),
                                (float*)(ws + OFF_NQ), (float*)(ws + OFF_NK));
  kdwv<<<3072, 256, 0, stream>>>((const unsigned short*)(ws + OFF_V), wdw, bdw,
                                 ws + OFF_XT);
  kattn<<<64, 256, 0, stream>>>((const float*)(ws + OFF_G), (const float*)(ws + OFF_NQ),
                                (const float*)(ws + OFF_NK), temp, wproj, ws + OFF_W2);
  kpos<<<3072, 256, 0, stream>>>(ws + OFF_XT, wpos1, wpos2,
                                 (unsigned short*)(ws + OFF_QK));
  kproj<<<1536, 256, 0, stream>>>(ws + OFF_XT, ws + OFF_W2, bproj,
                                  (const unsigned short*)(ws + OFF_QK), (float*)d_out);
}